// Round 1
// baseline (452.236 us; speedup 1.0000x reference)
//
#include <hip/hip_runtime.h>

// Problem: T=2048, B=16, N=2048, binary fp32 spikes, duration=100.
// out[t,b,n] = 1 if any spike in window [t-duration+1, t], else 0.
// Streaming scan over time with "last spike time" state; time is split
// into chunks of C=256 with a (duration-1)-step halo re-scan so we get
// 1024 independent blocks (16 waves/CU) instead of a serial 2048-scan.

#define T_TOTAL 2048
#define M_COLS  (16 * 2048)   // B*N, contiguous fastest axis (b,n) flattened
#define CHUNK   256           // time steps per thread; halo overhead 99/256

__global__ __launch_bounds__(256) void psp_scan_kernel(
    const float* __restrict__ x,
    const int*  __restrict__ dur_p,
    float* __restrict__ out)
{
    const int col = blockIdx.x * blockDim.x + threadIdx.x;   // 0 .. M_COLS-1
    const int t0  = blockIdx.y * CHUNK;
    const int duration = dur_p[0];                           // uniform scalar load

    // sentinel: guarantees (t - last) >= duration for all t >= t0 until a spike
    int last = t0 - duration;

    int tstart = t0 - duration + 1;
    if (tstart < 0) tstart = 0;

    const float* xc = x + col;
    float* oc = out + col;

    // Halo: recover "time of last spike" entering this chunk.
    for (int t = tstart; t < t0; ++t) {
        float v = xc[t * M_COLS];
        if (v != 0.0f) last = t;
    }

    // Main chunk: scan + emit.
    #pragma unroll 4
    for (int t = t0; t < t0 + CHUNK; ++t) {
        float v = xc[t * M_COLS];
        if (v != 0.0f) last = t;
        oc[t * M_COLS] = (t - last < duration) ? 1.0f : 0.0f;
    }
}

extern "C" void kernel_launch(void* const* d_in, const int* in_sizes, int n_in,
                              void* d_out, int out_size, void* d_ws, size_t ws_size,
                              hipStream_t stream) {
    const float* x     = (const float*)d_in[0];
    const int*   dur_p = (const int*)d_in[1];
    float*       out   = (float*)d_out;

    dim3 grid(M_COLS / 256, T_TOTAL / CHUNK);   // (128, 8) = 1024 blocks
    dim3 block(256);
    psp_scan_kernel<<<grid, block, 0, stream>>>(x, dur_p, out);
}